// Round 15
// baseline (122.216 us; speedup 1.0000x reference)
//
#include <hip/hip_runtime.h>
#include <stdint.h>

#define BATCH 32
#define H 512
#define W 512
#define NACC 16
#define TH 32              // center rows per tile
#define HALO 9             // coverage steps a=1..9
#define RH (TH + 2*HALO)   // 50 rows incl. halo
#define NWORDS (RH*8)      // 400 mask words per image
#define NT 1024
#define NW (NT/64)         // 16 waves
#define NTILE (H/TH)       // 16
#define NBLK (NTILE*BATCH) // 512 blocks = 2/CU

// part[fid*NACC + k] per-block partials (no atomics, deterministic):
//  0: sum(p*g)  1: sum(p)  2: sum(g)
//  3: cnt_pe 4: cnt_pm 5: cnt_pj  6: cnt_ge 7: cnt_gm 8: cnt_gj
//  9: int_e 10: int_m 11: int_j
// 12: dsum_p2g 13: cnt_p2g 14: dsum_g2p 15: cnt_g2p

// LB(NT,8) forces 64-VGPR budget -> spill storm (R7/R8). LB(NT,4) is safe.
__global__ __launch_bounds__(NT, 4) void fused_kernel(
    const float* __restrict__ pred, const float* __restrict__ gt,
    float* __restrict__ part)
{
    __shared__ uint64_t MpS[NWORDS + 2];   // single-buffer + pad word each end
    __shared__ uint64_t MgS[NWORDS + 2];
    __shared__ float    EC[2][TH];         // pred colsums at cols 255|256
    __shared__ float    redf[NW][2];
    __shared__ unsigned redu[NW][6];

    uint64_t* Mp = MpS + 1;   // flat index o = row*8 + word
    uint64_t* Mg = MgS + 1;

    // fid = tile*32 + b: vertically-adjacent tiles of one image are 32 apart
    // => same XCD under mod-8 round-robin dispatch (halo rows share L2).
    int fid  = blockIdx.x;
    int b    = fid & 31;
    int tile = fid >> 5;

    const float* pimg = pred + (size_t)b * H * W;
    const float* gimg = gt   + (size_t)b * H * W;
    int y0 = tile * TH;
    int tid = threadIdx.x, lane = tid & 63, wid = tid >> 6;

    // ---- Phase 1: ballot masks + dice sums, rows y0-9..y0+40.
    // 400 word-tasks, x4 unroll: 8 global loads in flight per wave iteration.
    float v0 = 0.f, v1 = 0.f;
    for (int s0 = wid; s0 < NWORDS; s0 += 4 * NW) {
        float vp[4], vg[4];
        #pragma unroll
        for (int u = 0; u < 4; ++u) {
            int s = s0 + u * NW;
            vp[u] = 0.f; vg[u] = 0.f;
            int ry = y0 - HALO + (s >> 3);
            if (s < NWORDS && (unsigned)ry < (unsigned)H) {
                int i0 = ry * W + (s & 7) * 64 + lane;
                vp[u] = pimg[i0]; vg[u] = gimg[i0];
            }
        }
        #pragma unroll
        for (int u = 0; u < 4; ++u) {
            int s = s0 + u * NW;
            if (s < NWORDS) {                 // wave-uniform
                unsigned long long mp = __ballot(vp[u] > 0.5f);
                unsigned long long mg = __ballot(vg[u] > 0.5f);
                if (lane == 0) { Mp[s] = mp; Mg[s] = mg; }
                int r = s >> 3;
                if (r >= HALO && r < HALO + TH) {
                    v1 += vp[u];
                    v0 += (vg[u] > 0.5f) ? vp[u] : 0.f;
                }
            }
        }
    }
    if (tid == 0) { MpS[0] = 0; MpS[NWORDS + 1] = 0; MgS[0] = 0; MgS[NWORDS + 1] = 0; }

    bool isStencil = tid >= 512;
    int sidx = tid & 511;
    int qi = sidx & 127, band = sidx >> 7;   // band 0..3
    // stencil waves: rows y0 + band*6, 6 rows. distance waves: y0+24+band*2, 2 rows.
    int ysS = y0 + band * 6;
    int ysD = y0 + 24 + band * 2;

    // Stencil-wave pre-barrier prefetch (latency overlaps the barrier drain)
    int x4 = qi * 4;
    float4 pm4 = make_float4(0, 0, 0, 0), pc4 = make_float4(0, 0, 0, 0);
    if (isStencil) {
        if (ysS > 0) pm4 = *(const float4*)(pimg + (size_t)(ysS - 1) * W + x4);
        pc4 = *(const float4*)(pimg + (size_t)ysS * W + x4);
    }

    // pred edge colsums (cols 255,256) for the cross-wave stencil halo
    if (tid < 2 * TH) {
        int c = tid >> 5, r = tid & (TH - 1);
        int y = y0 + r, col = 255 + c;
        float sum = (y > 0     ? pimg[(size_t)(y - 1) * W + col] : 0.f)
                  +              pimg[(size_t)y * W + col]
                  + (y < H - 1 ? pimg[(size_t)(y + 1) * W + col] : 0.f);
        EC[c][r] = sum;
    }
    __syncthreads();
    // ======== NO MORE BARRIERS until the final reduce ========

    uint64_t cpack = 0ULL;      // classification counters, 7-bit fields
    int dsum = 0, dcnt = 0;     // distance waves only

    int wdx = qi >> 4;          // gt word for this quad
    int ss = (qi & 15) * 4;     // bit offset of x4 in word
    auto win6 = [&](int rb) -> uint32_t {
        const uint64_t* row = &Mg[rb * 8];
        uint64_t bm = row[wdx];
        if (ss == 0) {
            uint64_t lo = wdx ? row[wdx - 1] : 0ULL;
            return (uint32_t)(((bm << 1) | (lo >> 63)) & 0x3FULL);
        }
        uint32_t v = (uint32_t)((bm >> (ss - 1)) & 0x3FULL);
        if (ss == 60) {
            uint64_t hi = (wdx < 7) ? row[wdx + 1] : 0ULL;
            v |= ((uint32_t)hi & 1u) << 5;
        }
        return v;
    };
    auto do_stencil = [&](int ys, int nrows, float4 m4, float4 c4) {
        int rb0 = (ys - y0) + HALO - 1;       // bit-row of (ys-1)
        uint32_t wU = win6(rb0), wM = win6(rb0 + 1);
        for (int r = 0; r < nrows; ++r) {
            int y = ys + r;
            float4 pp4 = (y < H - 1) ? *(const float4*)(pimg + (size_t)(y + 1) * W + x4)
                                     : make_float4(0, 0, 0, 0);
            uint32_t wD = win6(rb0 + 2 + r);
            int ry = (ys - y0) + r;

            float ps[6];
            ps[1] = m4.x + c4.x + pp4.x; ps[2] = m4.y + c4.y + pp4.y;
            ps[3] = m4.z + c4.z + pp4.z; ps[4] = m4.w + c4.w + pp4.w;
            float psl = __shfl_up(ps[4], 1, 64);
            float psr = __shfl_down(ps[1], 1, 64);
            if (lane == 0)  psl = (qi == 0)   ? 0.f : EC[0][ry];
            if (lane == 63) psr = (qi == 127) ? 0.f : EC[1][ry];
            ps[0] = psl; ps[5] = psr;

            float pcv[4] = {c4.x, c4.y, c4.z, c4.w};
            #pragma unroll
            for (int j = 0; j < 4; ++j) {
                float np = ps[j] + ps[j + 1] + ps[j + 2] - pcv[j];
                bool pon = pcv[j] > 0.5f;
                bool pe  = pon && (np == 1.f);
                bool pmb = pon && (np == 2.f);
                bool pjb = pon && (np > 2.f);
                uint32_t n9 = ((wU >> j) & 7u) | (((wM >> j) & 7u) << 3) | (((wD >> j) & 7u) << 6);
                uint32_t cen = (wM >> (j + 1)) & 1u;
                int ng = __popc(n9) - (int)cen;
                bool gon = cen != 0u;
                bool ge  = gon && (ng == 1);
                bool gmb = gon && (ng == 2);
                bool gjb = gon && (ng > 2);
                cpack += (uint64_t)pe
                       | ((uint64_t)pmb << 7)
                       | ((uint64_t)pjb << 14)
                       | ((uint64_t)ge  << 21)
                       | ((uint64_t)gmb << 28)
                       | ((uint64_t)gjb << 35)
                       | ((uint64_t)(pe  && ge)  << 42)
                       | ((uint64_t)(pmb && gmb) << 49)
                       | ((uint64_t)(pjb && gjb) << 56);
            }
            m4 = c4; c4 = pp4; wU = wM; wM = wD;
        }
    };

    if (isStencil) {
        do_stencil(ysS, 6, pm4, pc4);
    } else {
        // ---- Distance: barrier-free register dilation (verified R10-R14).
        // C_a = S_a(V_a); incremental C_a = C_{a-1}|S_{a-1}(N_a)|shift_a(V_a)
        bool isP = tid < 256;                  // waves 0-3: p2g; 4-7: g2p
        int di = tid & 255;
        int o  = (HALO + (di >> 3)) * 8 + (di & 7);  // rc in [9,40]
        int w  = di & 7;
        bool wL = (w > 0), wR = (w < 7);
        const uint64_t* MT = isP ? Mp : Mg;
        const uint64_t* MV = isP ? Mg : Mp;

        uint64_t T = MT[o];
        dcnt = __popcll(T);
        dsum = dcnt;                           // a=0 baseline (dist >= 1)
        uint64_t VM = MV[o];
        uint64_t VL = wL ? MV[o - 1] : 0ULL;
        uint64_t VR = wR ? MV[o + 1] : 0ULL;
        uint64_t C = VM;

        #pragma unroll
        for (int a = 1; a <= 9; ++a) {
            int lo = o - 8 * a, hi = o + 8 * a;
            uint64_t NM = MV[lo] | MV[hi];
            uint64_t NL = wL ? (MV[lo - 1] | MV[hi - 1]) : 0ULL;
            uint64_t NR = wR ? (MV[lo + 1] | MV[hi + 1]) : 0ULL;
            uint64_t SL = NL, SM = NM, SR = NR;
            const int m = a - 1;
            if (m >= 1) {
                SM |= (SM << 1) | (SM >> 1) | (SL >> 63) | (SR << 63);
                SL |= SL << 1; SR |= SR >> 1;
            }
            if (m >= 2) {
                const int s = (m == 2) ? 1 : 2;
                SM |= (SM << s) | (SM >> s) | (SL >> (64 - s)) | (SR << (64 - s));
                SL |= SL << s; SR |= SR >> s;
            }
            if (m >= 4) {
                const int s = (m - 3 < 4) ? (m - 3) : 4;
                SM |= (SM << s) | (SM >> s) | (SL >> (64 - s)) | (SR << (64 - s));
                SL |= SL << s; SR |= SR >> s;
            }
            if (m >= 8) {
                const int s = m - 7;
                SM |= (SM << s) | (SM >> s) | (SL >> (64 - s)) | (SR << (64 - s));
                SL |= SL << s; SR |= SR >> s;
            }
            C |= SM;
            VL |= NL; VM |= NM; VR |= NR;
            C |= (VM << a) | (VM >> a) | (VL >> (64 - a)) | (VR << (64 - a));
            dsum += __popcll(T & ~C);
        }
        // ---- then this half's 2 stencil rows (rows 24..31)
        float4 m4 = make_float4(0, 0, 0, 0);
        if (ysD > 0) m4 = *(const float4*)(pimg + (size_t)(ysD - 1) * W + x4);
        float4 c4 = *(const float4*)(pimg + (size_t)ysD * W + x4);
        do_stencil(ysD, 2, m4, c4);
    }

    // ---- Packed reductions: 2 floats + 6 u32 (16-bit fields; wave sums
    // bounded: counters <= 64*24, dsum <= 64*640 < 2^16) -> 8 butterflies.
    unsigned c3  = (unsigned)( cpack        & 0x7F);
    unsigned c4v = (unsigned)((cpack >> 7 ) & 0x7F);
    unsigned c5  = (unsigned)((cpack >> 14) & 0x7F);
    unsigned c6  = (unsigned)((cpack >> 21) & 0x7F);
    unsigned c7  = (unsigned)((cpack >> 28) & 0x7F);
    unsigned c8  = (unsigned)((cpack >> 35) & 0x7F);
    unsigned c9  = (unsigned)((cpack >> 42) & 0x7F);
    unsigned c10 = (unsigned)((cpack >> 49) & 0x7F);
    unsigned c11 = (unsigned)((cpack >> 56) & 0x7F);
    unsigned r0 = c3 | (c4v << 16);
    unsigned r1 = c5 | (c6 << 16);
    unsigned r2 = c7 | (c8 << 16);
    unsigned r3 = c9 | (c10 << 16);
    unsigned r4 = c11;
    unsigned r5 = isStencil ? 0u : ((unsigned)dsum | ((unsigned)dcnt << 16));
    #pragma unroll
    for (int off = 32; off; off >>= 1) {
        v0 += __shfl_down(v0, off, 64);
        v1 += __shfl_down(v1, off, 64);
        r0 += __shfl_down(r0, off, 64);
        r1 += __shfl_down(r1, off, 64);
        r2 += __shfl_down(r2, off, 64);
        r3 += __shfl_down(r3, off, 64);
        r4 += __shfl_down(r4, off, 64);
        r5 += __shfl_down(r5, off, 64);
    }
    if (lane == 0) {
        redf[wid][0] = v0; redf[wid][1] = v1;
        redu[wid][0] = r0; redu[wid][1] = r1; redu[wid][2] = r2;
        redu[wid][3] = r3; redu[wid][4] = r4; redu[wid][5] = r5;
    }
    __syncthreads();
    if (tid < 16) {
        int k = tid;
        float s = 0.f;
        if (k < 2) {
            #pragma unroll
            for (int wv = 0; wv < NW; ++wv) s += redf[wv][k];
        } else if (k == 2) {               // sum(g) = dcnt_g (waves 4-7 high)
            unsigned u = 0;
            for (int wv = 4; wv < 8; ++wv) u += redu[wv][5] >> 16;
            s = (float)u;
        } else if (k <= 10) {              // counters from ALL waves
            int pair = (k - 3) >> 1, hi = (k - 3) & 1;
            unsigned u = 0;
            for (int wv = 0; wv < NW; ++wv) u += (redu[wv][pair] >> (hi * 16)) & 0xFFFFu;
            s = (float)u;
        } else if (k == 11) {
            unsigned u = 0;
            for (int wv = 0; wv < NW; ++wv) u += redu[wv][4];
            s = (float)u;
        } else {                           // 12..15: dsum/dcnt p (0-3) g (4-7)
            int base = (k < 14) ? 0 : 4, hi = k & 1;
            unsigned u = 0;
            for (int wv = base; wv < base + 4; ++wv)
                u += (redu[wv][5] >> (hi * 16)) & 0xFFFFu;
            s = (float)u;
        }
        part[fid * NACC + k] = s;
    }
}

// ---------------------------------------------------------------------------
// Final: reduce 512x16 partials -> 32x16 -> scalar. One block, deterministic.
// ---------------------------------------------------------------------------
__global__ __launch_bounds__(512) void final_kernel(
    const float* __restrict__ part, float* __restrict__ out)
{
    __shared__ float sacc[BATCH][NACC];
    __shared__ float tri[BATCH][3];
    int t = threadIdx.x;
    {
        int b = t >> 4, k = t & 15;
        float s = 0.f;
        #pragma unroll 4
        for (int j = 0; j < NTILE; ++j)            // fid = j*32 + b
            s += part[((j << 5) + b) * NACC + k];
        sacc[b][k] = s;
    }
    __syncthreads();
    if (t < BATCH) {
        const float* a = sacc[t];
        float inter = a[0], psum = a[1], gsum = a[2];
        float dice = (2.f * inter + 1.f) / (psum + gsum + 1.f);

        float pe = a[3], pm = a[4], pj = a[5];
        float ge = a[6], gm = a[7], gj = a[8];
        float ie = a[9], im = a[10], ij = a[11];
        float e_iou = (ie + 1.f) / (pe + ge - ie + 1.f);
        float m_iou = (im + 1.f) / (pm + gm - im + 1.f);
        float j_iou = (ij + 1.f) / (pj + gj - ij + 1.f);
        float total = ge + gj + gm + 1.f;
        float sloss = 1.f - ((ge / total) * e_iou + (gj / total) * j_iou + (gm / total) * m_iou);

        float p2g = a[12] / (a[13] + 1.f);
        float g2p = a[14] / (a[15] + 1.f);
        float med = ((p2g + g2p) * 0.5f) / 10.f;
        tri[t][0] = dice; tri[t][1] = sloss; tri[t][2] = med;
    }
    __syncthreads();
    if (t == 0) {
        float dice = 0.f, sloss = 0.f, med = 0.f;
        for (int b = 0; b < BATCH; ++b) {
            dice += tri[b][0]; sloss += tri[b][1]; med += tri[b][2];
        }
        float dice_loss  = 1.f - dice / (float)BATCH;
        float structural = sloss / (float)BATCH;
        float medial     = med / (float)BATCH;
        float avg = (dice_loss + structural + medial) / 3.f;
        float r = dice_loss  / (dice_loss  + 1.f) * avg
                + structural / (structural + 1.f) * avg
                + medial     / (medial     + 1.f) * avg;
        out[0] = r;
    }
}

extern "C" void kernel_launch(void* const* d_in, const int* in_sizes, int n_in,
                              void* d_out, int out_size, void* d_ws, size_t ws_size,
                              hipStream_t stream)
{
    const float* pred = (const float*)d_in[0];
    const float* gt   = (const float*)d_in[1];
    float* part = (float*)d_ws;
    float* out  = (float*)d_out;

    fused_kernel<<<dim3(NBLK), NT, 0, stream>>>(pred, gt, part);
    final_kernel<<<1, 512, 0, stream>>>(part, out);
}